// Round 1
// baseline (150.184 us; speedup 1.0000x reference)
//
#include <hip/hip_runtime.h>

// BSRTransform: block-shuffle + per-block small rotation + bilinear sampling.
// Shapes (compile-time constants from the reference):
//   x:      (B=16, C=3, H=224, W=224) fp32
//   w_lens: (NC=20, NB=2) i32      h_lens: (20,2) i32
//   perm_w: (20,2) i32             perm_h: (20,2) i32
//   angles: (NC=20, NB=2, B=16) fp32
//   out:    (NC*B=320, C=3, H=224, W=224) fp32
#define NC 20
#define NB 2
#define BB 16
#define CC 3
#define HH 224
#define WW 224

__global__ __launch_bounds__(256) void bsr_kernel(
    const float* __restrict__ x,
    const int*   __restrict__ w_lens,
    const int*   __restrict__ h_lens,
    const int*   __restrict__ perm_w,
    const int*   __restrict__ perm_h,
    const float* __restrict__ angles,
    float*       __restrict__ out)
{
    const unsigned NP = (unsigned)NC * BB * HH * WW;   // 16,056,320
    unsigned idx = blockIdx.x * blockDim.x + threadIdx.x;
    if (idx >= NP) return;

    // idx -> (c, b, i, j); consecutive threads share (c,b,i), walk j.
    unsigned j = idx % WW;
    unsigned t = idx / WW;
    unsigned i = t % HH;
    t /= HH;
    unsigned b = t % BB;
    unsigned c = t / BB;

    // --- per-copy block metadata (NB==2 => searchsorted is one compare) ---
    int wl0 = w_lens[c * NB + 0], wl1 = w_lens[c * NB + 1];
    int pw0 = perm_w[c * NB + 0], pw1 = perm_w[c * NB + 1];
    int sw0 = (pw0 == 0) ? wl0 : wl1;          // width of first OUTPUT block
    int k   = ((int)j >= sw0) ? 1 : 0;         // output w-block index
    int wi  = k ? pw1 : pw0;                   // source w-block index
    int loc_j = (int)j - (k ? sw0 : 0);        // local col in block
    int Wb  = wi ? wl1 : wl0;                  // block width
    int sj0 = wi ? wl0 : 0;                    // source block col start

    int hl0 = h_lens[c * NB + 0], hl1 = h_lens[c * NB + 1];
    int ph0 = perm_h[c * NB + 0], ph1 = perm_h[c * NB + 1];
    int sh0 = (ph0 == 0) ? hl0 : hl1;
    int m   = ((int)i >= sh0) ? 1 : 0;
    int hj  = m ? ph1 : ph0;
    int loc_i = (int)i - (m ? sh0 : 0);
    int Hb  = hj ? hl1 : hl0;
    int si0 = hj ? hl0 : 0;

    // --- rotation about block center ---
    float cx = (float)(Wb - 1) * 0.5f;
    float cy = (float)(Hb - 1) * 0.5f;
    float dx = (float)loc_j - cx;
    float dy = (float)loc_i - cy;

    // angle indexed by OUTPUT w-block index k (per reference), and batch b
    float ang = angles[(c * NB + k) * BB + b];
    float ca = __cosf(ang);
    float sa = __sinf(ang);

    float src_x = cx + ca * dx + sa * dy;
    float src_y = cy - sa * dx + ca * dy;

    float flx = floorf(src_x);
    float fly = floorf(src_y);
    int x0 = (int)flx;
    int y0 = (int)fly;
    float fx = src_x - flx;
    float fy = src_y - fly;
    int x1 = x0 + 1, y1 = y0 + 1;

    // validity (block-local) and clipped global coords
    float vx0 = (x0 >= 0 && x0 < Wb) ? 1.0f : 0.0f;
    float vx1 = (x1 >= 0 && x1 < Wb) ? 1.0f : 0.0f;
    float vy0 = (y0 >= 0 && y0 < Hb) ? 1.0f : 0.0f;
    float vy1 = (y1 >= 0 && y1 < Hb) ? 1.0f : 0.0f;
    int gx0 = sj0 + min(max(x0, 0), Wb - 1);
    int gx1 = sj0 + min(max(x1, 0), Wb - 1);
    int gy0 = si0 + min(max(y0, 0), Hb - 1);
    int gy1 = si0 + min(max(y1, 0), Hb - 1);

    float w00 = (1.0f - fx) * (1.0f - fy) * vx0 * vy0;
    float w10 = fx * (1.0f - fy) * vx1 * vy0;
    float w01 = (1.0f - fx) * fy * vx0 * vy1;
    float w11 = fx * fy * vx1 * vy1;

    const float* xb = x + (unsigned)b * (CC * HH * WW);
    unsigned r0 = (unsigned)gy0 * WW;
    unsigned r1 = (unsigned)gy1 * WW;
    float* ob = out + (unsigned)(c * BB + b) * (CC * HH * WW) + i * WW + j;

#pragma unroll
    for (int ch = 0; ch < CC; ++ch) {
        const float* xp = xb + (unsigned)ch * (HH * WW);
        float v = w00 * xp[r0 + gx0]
                + w10 * xp[r0 + gx1]
                + w01 * xp[r1 + gx0]
                + w11 * xp[r1 + gx1];
        ob[(unsigned)ch * (HH * WW)] = v;
    }
}

extern "C" void kernel_launch(void* const* d_in, const int* in_sizes, int n_in,
                              void* d_out, int out_size, void* d_ws, size_t ws_size,
                              hipStream_t stream) {
    const float* x      = (const float*)d_in[0];
    const int*   w_lens = (const int*)d_in[1];
    const int*   h_lens = (const int*)d_in[2];
    const int*   perm_w = (const int*)d_in[3];
    const int*   perm_h = (const int*)d_in[4];
    const float* angles = (const float*)d_in[5];
    float* out = (float*)d_out;

    const unsigned NP = (unsigned)NC * BB * HH * WW;
    const int block = 256;
    const int grid = (int)((NP + block - 1) / block);
    bsr_kernel<<<grid, block, 0, stream>>>(x, w_lens, h_lens, perm_w, perm_h, angles, out);
}

// Round 2
// 121.176 us; speedup vs baseline: 1.2394x; 1.2394x over previous
//
#include <hip/hip_runtime.h>

// BSRTransform: block-shuffle + per-block small rotation + bilinear sampling.
//   x:      (B=16, C=3, H=224, W=224) fp32   (9.6 MB)
//   out:    (NC*B=320, C=3, H=224, W=224) fp32  (192.7 MB)
// R2: XCD-pinned block remap (each XCD owns b in {xcd, xcd+8}; c-major inside)
//     -> per-XCD read working set = one 602 KB b-slice, L2-resident.
//     c,b now wave-uniform -> metadata in SGPRs. Non-temporal stores keep the
//     write stream from evicting x out of L2.
#define NC 20
#define NB 2
#define BB 16
#define CC 3
#define HH 224
#define WW 224
#define NXCD 8
#define PIX_PER_PLANE (HH * WW)          // 50176
#define BLOCKS_PER_PLANE (PIX_PER_PLANE / 256)  // 196
#define BLOCKS_PER_B (NC * BLOCKS_PER_PLANE)    // 3920 blocks for one b (all c)
#define BSEL_PER_XCD (BB / NXCD)         // 2

__global__ __launch_bounds__(256) void bsr_kernel(
    const float* __restrict__ x,
    const int*   __restrict__ w_lens,
    const int*   __restrict__ h_lens,
    const int*   __restrict__ perm_w,
    const int*   __restrict__ perm_h,
    const float* __restrict__ angles,
    float*       __restrict__ out)
{
    // blockIdx.x % 8 == XCD (round-robin dispatch model). XCD x owns b = x, x+8.
    unsigned xcd   = blockIdx.x & (NXCD - 1);
    unsigned inner = blockIdx.x >> 3;            // 0 .. 7839
    unsigned bsel  = inner / BLOCKS_PER_B;       // 0 or 1
    unsigned rem   = inner - bsel * BLOCKS_PER_B;
    unsigned c     = rem / BLOCKS_PER_PLANE;     // copy index (uniform)
    unsigned pblk  = rem - c * BLOCKS_PER_PLANE; // pixel-block within plane
    unsigned b     = xcd + (bsel << 3);          // batch index (uniform)

    unsigned pix = pblk * 256u + threadIdx.x;    // 0 .. 50175
    unsigned i = pix / WW;
    unsigned j = pix - i * WW;

    // --- per-copy block metadata (uniform -> scalar loads) ---
    int wl0 = w_lens[c * NB + 0], wl1 = w_lens[c * NB + 1];
    int pw0 = perm_w[c * NB + 0], pw1 = perm_w[c * NB + 1];
    int sw0 = (pw0 == 0) ? wl0 : wl1;          // width of first OUTPUT block
    int k   = ((int)j >= sw0) ? 1 : 0;         // output w-block index (per-thread)
    int wi  = k ? pw1 : pw0;                   // source w-block index
    int loc_j = (int)j - (k ? sw0 : 0);
    int Wb  = wi ? wl1 : wl0;
    int sj0 = wi ? wl0 : 0;

    int hl0 = h_lens[c * NB + 0], hl1 = h_lens[c * NB + 1];
    int ph0 = perm_h[c * NB + 0], ph1 = perm_h[c * NB + 1];
    int sh0 = (ph0 == 0) ? hl0 : hl1;
    int m   = ((int)i >= sh0) ? 1 : 0;
    int hj  = m ? ph1 : ph0;
    int loc_i = (int)i - (m ? sh0 : 0);
    int Hb  = hj ? hl1 : hl0;
    int si0 = hj ? hl0 : 0;

    // --- rotation about block center ---
    float cx = (float)(Wb - 1) * 0.5f;
    float cy = (float)(Hb - 1) * 0.5f;
    float dx = (float)loc_j - cx;
    float dy = (float)loc_i - cy;

    // both candidate angles are uniform; select per-thread by k
    float a0 = angles[(c * NB + 0) * BB + b];
    float a1 = angles[(c * NB + 1) * BB + b];
    float ang = k ? a1 : a0;
    float ca = __cosf(ang);
    float sa = __sinf(ang);

    float src_x = cx + ca * dx + sa * dy;
    float src_y = cy - sa * dx + ca * dy;

    float flx = floorf(src_x);
    float fly = floorf(src_y);
    int x0 = (int)flx;
    int y0 = (int)fly;
    float fx = src_x - flx;
    float fy = src_y - fly;
    int x1 = x0 + 1, y1 = y0 + 1;

    float vx0 = (x0 >= 0 && x0 < Wb) ? 1.0f : 0.0f;
    float vx1 = (x1 >= 0 && x1 < Wb) ? 1.0f : 0.0f;
    float vy0 = (y0 >= 0 && y0 < Hb) ? 1.0f : 0.0f;
    float vy1 = (y1 >= 0 && y1 < Hb) ? 1.0f : 0.0f;
    int gx0 = sj0 + min(max(x0, 0), Wb - 1);
    int gx1 = sj0 + min(max(x1, 0), Wb - 1);
    int gy0 = si0 + min(max(y0, 0), Hb - 1);
    int gy1 = si0 + min(max(y1, 0), Hb - 1);

    float w00 = (1.0f - fx) * (1.0f - fy) * vx0 * vy0;
    float w10 = fx * (1.0f - fy) * vx1 * vy0;
    float w01 = (1.0f - fx) * fy * vx0 * vy1;
    float w11 = fx * fy * vx1 * vy1;

    const float* xb = x + b * (CC * HH * WW);
    unsigned r0 = (unsigned)gy0 * WW;
    unsigned r1 = (unsigned)gy1 * WW;
    float* ob = out + (c * BB + b) * (unsigned)(CC * HH * WW) + i * WW + j;

#pragma unroll
    for (int ch = 0; ch < CC; ++ch) {
        const float* xp = xb + (unsigned)ch * PIX_PER_PLANE;
        float v = w00 * xp[r0 + gx0]
                + w10 * xp[r0 + gx1]
                + w01 * xp[r1 + gx0]
                + w11 * xp[r1 + gx1];
        __builtin_nontemporal_store(v, ob + (unsigned)ch * PIX_PER_PLANE);
    }
}

extern "C" void kernel_launch(void* const* d_in, const int* in_sizes, int n_in,
                              void* d_out, int out_size, void* d_ws, size_t ws_size,
                              hipStream_t stream) {
    const float* x      = (const float*)d_in[0];
    const int*   w_lens = (const int*)d_in[1];
    const int*   h_lens = (const int*)d_in[2];
    const int*   perm_w = (const int*)d_in[3];
    const int*   perm_h = (const int*)d_in[4];
    const float* angles = (const float*)d_in[5];
    float* out = (float*)d_out;

    const unsigned NP = (unsigned)NC * BB * HH * WW;   // 16,056,320
    const int block = 256;
    const int grid = (int)(NP / block);                // 62,720 (exact)
    bsr_kernel<<<grid, block, 0, stream>>>(x, w_lens, h_lens, perm_w, perm_h, angles, out);
}